// Round 7
// baseline (217.260 us; speedup 1.0000x reference)
//
#include <hip/hip_runtime.h>
#include <hip/hip_bf16.h>

// Problem constants (SparseMoE: D=512, H=2048, O=512, E=8, K=2, CF=1.0)
#define NTOK 16384
#define DDIM 512
#define HDIM 2048
#define ODIM 512
#define NE 8
#define CAP 2048   // max(int(N/E*CF), 4) = 2048

typedef __attribute__((ext_vector_type(8))) short short8v;
typedef __attribute__((ext_vector_type(4))) short short4v;
typedef __attribute__((ext_vector_type(8))) unsigned short ushort8v;
typedef __attribute__((ext_vector_type(4))) float f32x4;

static __device__ __forceinline__ unsigned short f2bf(float f) {
  __hip_bfloat16 h = __float2bfloat16(f);
  return __builtin_bit_cast(unsigned short, h);
}

// async global->LDS, 16B per lane; LDS dest = wave-uniform base + lane*16
#define GLOAD_LDS16(gp, lp)                                               \
  __builtin_amdgcn_global_load_lds(                                       \
      (const __attribute__((address_space(1))) void*)(gp),                \
      (__attribute__((address_space(3))) void*)(lp), 16, 0, 0)

// ---------------- fused prep: transpose w1, transpose w2, gating
__device__ __forceinline__ void transpose_block(const float* __restrict__ src,
                                                __hip_bfloat16* __restrict__ dst,
                                                int R, int C, int b) {
  __shared__ float tile[32][33];
  int nx = C >> 5, ny = R >> 5;
  int x = b % nx, y = (b / nx) % ny, e = b / (nx * ny);
  size_t base = (size_t)e * R * C;
  int c0 = x * 32, r0 = y * 32;
  int tx = threadIdx.x & 31, ty = threadIdx.x >> 5;
#pragma unroll
  for (int i = 0; i < 32; i += 8)
    tile[ty + i][tx] = src[base + (size_t)(r0 + ty + i) * C + c0 + tx];
  __syncthreads();
#pragma unroll
  for (int i = 0; i < 32; i += 8)
    dst[base + (size_t)(c0 + ty + i) * R + r0 + tx] = __float2bfloat16(tile[tx][ty + i]);
}

__global__ void k_prep(const float* __restrict__ x, const float* __restrict__ gw,
                       const float* __restrict__ gb, const float* __restrict__ w1,
                       __hip_bfloat16* __restrict__ w1t, const float* __restrict__ w2,
                       __hip_bfloat16* __restrict__ w2t, float* __restrict__ gate_probs,
                       int2* __restrict__ tk_e, float2* __restrict__ tk_w,
                       int* __restrict__ token_slot) {
  int b = blockIdx.x;
  if (b < 8192) { transpose_block(w1, w1t, DDIM, HDIM, b); return; }
  if (b < 16384) { transpose_block(w2, w2t, HDIM, ODIM, b - 8192); return; }
  b -= 16384;
  __shared__ float gws[DDIM * 9];
  int tid = threadIdx.x;
  for (int i = tid; i < DDIM * NE; i += 256) {
    int d = i >> 3, e = i & 7;
    gws[d * 9 + e] = gw[i];
  }
  __syncthreads();
  int wid = tid >> 6, lane = tid & 63;
  int t = b * 4 + wid;
  const float* xr = x + (size_t)t * DDIM;
  float acc[NE] = {0.f, 0.f, 0.f, 0.f, 0.f, 0.f, 0.f, 0.f};
#pragma unroll
  for (int j = 0; j < 8; ++j) {
    float xv = xr[lane + 64 * j];
    const float* g = &gws[(lane + 64 * j) * 9];
#pragma unroll
    for (int e = 0; e < NE; ++e) acc[e] += xv * g[e];
  }
#pragma unroll
  for (int e = 0; e < NE; ++e) {
#pragma unroll
    for (int off = 32; off > 0; off >>= 1) acc[e] += __shfl_xor(acc[e], off, 64);
  }
  if (lane == 0) {
    float p[NE];
    float m = -1e30f;
#pragma unroll
    for (int e = 0; e < NE; ++e) { p[e] = acc[e] + gb[e]; m = fmaxf(m, p[e]); }
    float s = 0.f;
#pragma unroll
    for (int e = 0; e < NE; ++e) { p[e] = expf(p[e] - m); s += p[e]; }
    float inv = 1.f / s;
#pragma unroll
    for (int e = 0; e < NE; ++e) { p[e] *= inv; gate_probs[(size_t)t * NE + e] = p[e]; }
    int i1 = 0; float p1 = p[0];
#pragma unroll
    for (int e = 1; e < NE; ++e) if (p[e] > p1) { p1 = p[e]; i1 = e; }
    int i2 = -1; float p2 = -1e30f;
#pragma unroll
    for (int e = 0; e < NE; ++e) if (e != i1 && p[e] > p2) { p2 = p[e]; i2 = e; }
    float wsum = p1 + p2;
    tk_e[t] = make_int2(i1, i2);
    tk_w[t] = make_float2(p1 / wsum, p2 / wsum);
    token_slot[2 * t] = -1;
    token_slot[2 * t + 1] = -1;
  }
}

// ---------------- dispatch: per-expert FCFS capacity assignment (block scan)
__global__ void k_dispatch(const int2* __restrict__ tk_e, int* __restrict__ token_slot,
                           int* __restrict__ expert_tokens) {
  int e = blockIdx.x;
  int tid = threadIdx.x;
  int lane = tid & 63, w = tid >> 6;   // 16 waves
  __shared__ int wave_cnt[16];
  int base = 0;
  for (int chunk = 0; chunk < NTOK / 1024; ++chunk) {
    int t = chunk * 1024 + tid;
    int2 te = tk_e[t];
    int k = (te.x == e) ? 0 : ((te.y == e) ? 1 : -1);
    bool flag = (k >= 0);
    unsigned long long m = __ballot(flag);
    int pre = __popcll(m & ((1ull << lane) - 1ull));
    __syncthreads();
    if (lane == 0) wave_cnt[w] = __popcll(m);
    __syncthreads();
    int off = 0, total = 0;
#pragma unroll
    for (int i = 0; i < 16; ++i) {
      off += (i < w) ? wave_cnt[i] : 0;
      total += wave_cnt[i];
    }
    int rank = base + off + pre;
    if (flag && rank < CAP) {
      expert_tokens[e * CAP + rank] = t;
      token_slot[2 * t + k] = e * CAP + rank;
    }
    base += total;
  }
  int nvalid = base < CAP ? base : CAP;
  for (int s = nvalid + tid; s < CAP; s += 1024)
    expert_tokens[e * CAP + s] = 0;  // padded slots: weight 0, never combined
}

// ---------------- gather: xg[e][c][:] = bf16(x[expert_tokens[e*CAP+c]][:])
__global__ void k_gather(const float* __restrict__ x,
                         const int* __restrict__ expert_tokens,
                         __hip_bfloat16* __restrict__ xg) {
  int tid = threadIdx.x, wid = tid >> 6, lane = tid & 63;
  int slot = blockIdx.x * 4 + wid;  // 0..E*CAP-1
  int tok = expert_tokens[slot];
  const float4* src = reinterpret_cast<const float4*>(x + (size_t)tok * DDIM) + lane * 2;
  float4 u = src[0], v = src[1];
  ushort8v o;
  o[0] = f2bf(u.x); o[1] = f2bf(u.y); o[2] = f2bf(u.z); o[3] = f2bf(u.w);
  o[4] = f2bf(v.x); o[5] = f2bf(v.y); o[6] = f2bf(v.z); o[7] = f2bf(v.w);
  *reinterpret_cast<ushort8v*>(xg + (size_t)slot * DDIM + lane * 8) = o;
}

// sigmoid-form tanh-GELU: |err vs exact erf-gelu| < ~1e-3, safe for bf16 out
static __device__ __forceinline__ float gelu_fast(float v) {
  float z = 1.5957691216057308f * (v + 0.044715f * v * v * v);
  return v / (1.f + __expf(-z));
}

// ---------------- hybrid-operand pipelined GEMM: BM=256 x BN=128, BK=32.
// A (weights) through LDS (3 bufs, global_load_lds, rule-21 swizzle).
// B (tokens) DIRECT global->VGPR per-lane fragment loads (AITER-style):
//   cuts LDS traffic 33% (demand 63 B/cyc < 85 ceiling), no B staging,
//   vmem pipe (idle) carries B. ONE barrier per K-step (3-buf rotation:
//   stage at step t targets buf (t-1)%3, read-complete before top-of-t bar).
// vmcnt FIFO per step: issue B(t+1) then stage A(t+2); top-of-step
// vmcnt(4) retires exactly A(t)+B(t), keeps A(t+1) in flight (T4).
// Counted lgkmcnt(4) lets MFMA(mm0-3) overlap tail A-reads.
template <int K, int M, bool GELU, typename OutT>
__global__ __launch_bounds__(256, 2) void k_gemm(
    const __hip_bfloat16* __restrict__ A, const __hip_bfloat16* __restrict__ B,
    const float* __restrict__ bias, OutT* __restrict__ C) {
  __shared__ char lds[3][16384];  // 3 x (256 rows x 64B) A tiles, 48 KB
  // XCD-aware bijective remap (grid size is a multiple of 8)
  int gx = gridDim.x, gy = gridDim.y;
  int lin = (blockIdx.z * gy + blockIdx.y) * gx + blockIdx.x;
  int total = gx * gy * (int)gridDim.z;
  int cpx = total >> 3;
  lin = (lin & 7) * cpx + (lin >> 3);
  int gxy = gx * gy;
  int e = lin / gxy;
  int rem = lin - e * gxy;
  int mt = rem / gx, nt = rem - mt * gx;

  const int m0 = mt * 256, n0 = nt * 128;
  const int tid = threadIdx.x;
  const int lane = tid & 63, wid = tid >> 6;
  const int wr = wid >> 1, wc = wid & 1;   // wave-tile 128 x 64
  const int lrow = lane & 15, kseg = lane >> 4;

  const int r0 = tid >> 2;                     // staging row 0..63
  const int sc = (tid & 3) ^ ((r0 >> 1) & 3);  // inverse-swizzled source k16
  const int cb = (tid & 192) * 16;             // wave-uniform LDS byte base
  const __hip_bfloat16* Ab = A + ((size_t)e * M + m0) * K;
  const char* Bbc = (const char*)(B + ((size_t)e * CAP + n0) * K);

  // per-lane B fragment byte offsets (row n0+wc*64+nn*16+lrow, k-chunk kseg)
  int vB[4];
#pragma unroll
  for (int nn = 0; nn < 4; ++nn)
    vB[nn] = (wc * 64 + nn * 16 + lrow) * (K * 2) + kseg * 16;

  // 4 gload_lds/thread/tile: A rows r0 + 64j
#define STAGE(buf, kk)                                                        \
  do {                                                                        \
    _Pragma("unroll")                                                         \
    for (int j = 0; j < 4; ++j)                                               \
      GLOAD_LDS16(Ab + (size_t)(r0 + 64 * j) * K + (kk) + sc * 8,             \
                  lds[buf] + j * 4096 + cb);                                  \
  } while (0)

#define LOADB(dst, kt)                                                        \
  do {                                                                        \
    _Pragma("unroll")                                                         \
    for (int nn = 0; nn < 4; ++nn)                                            \
      dst[nn] = *reinterpret_cast<const short8v*>(Bbc + vB[nn] + (kt) * 64);  \
  } while (0)

  // One K-step: consume B-set BC, load B-set BL for kt+1, stage A(kt+2)->sbuf
#define STEP(kt, abuf, sbuf, BC, BL)                                          \
  do {                                                                        \
    if ((kt) < T - 1) asm volatile("s_waitcnt vmcnt(4)" ::: "memory");        \
    else              asm volatile("s_waitcnt vmcnt(0)" ::: "memory");        \
    __builtin_amdgcn_s_barrier();                                             \
    _Pragma("unroll")                                                         \
    for (int mm = 0; mm < 8; ++mm) {                                          \
      int rr = wr * 128 + mm * 16 + lrow;                                     \
      int ks = kseg ^ ((rr >> 1) & 3);                                        \
      a[mm] = *reinterpret_cast<const short8v*>(lds[abuf] + rr * 64 + ks * 16); \
    }                                                                         \
    if ((kt) + 1 < T) LOADB(BL, (kt) + 1);                                    \
    if ((kt) + 2 < T) STAGE(sbuf, ((kt) + 2) * 32);                           \
    asm volatile("s_waitcnt lgkmcnt(4)" ::: "memory");                        \
    __builtin_amdgcn_sched_barrier(0);                                        \
    __builtin_amdgcn_s_setprio(1);                                            \
    _Pragma("unroll")                                                         \
    for (int mm = 0; mm < 4; ++mm)                                            \
      _Pragma("unroll")                                                       \
      for (int nn = 0; nn < 4; ++nn)                                          \
        acc[mm][nn] = __builtin_amdgcn_mfma_f32_16x16x32_bf16(                \
            a[mm], BC[nn], acc[mm][nn], 0, 0, 0);                             \
    asm volatile("s_waitcnt lgkmcnt(0)" ::: "memory");                        \
    __builtin_amdgcn_sched_barrier(0);                                        \
    _Pragma("unroll")                                                         \
    for (int mm = 4; mm < 8; ++mm)                                            \
      _Pragma("unroll")                                                       \
      for (int nn = 0; nn < 4; ++nn)                                          \
        acc[mm][nn] = __builtin_amdgcn_mfma_f32_16x16x32_bf16(                \
            a[mm], BC[nn], acc[mm][nn], 0, 0, 0);                             \
    __builtin_amdgcn_s_setprio(0);                                            \
  } while (0)

  f32x4 acc[8][4] = {};
  short8v a[8], bp[4], bq[4];
  const int T = K >> 5;  // 16 (GEMM1) or 64 (GEMM2); always even, >= 4

  // prologue FIFO: [A0, B0, A1] -> vmcnt(4) at step0 retires A0+B0
  STAGE(0, 0);
  LOADB(bp, 0);
  STAGE(1, 32);

  int bt = 0;
  for (int t = 0; t < T; t += 2) {
    int u1 = (bt == 2) ? 0 : bt + 1;   // (t+1) % 3
    int u2 = (u1 == 2) ? 0 : u1 + 1;   // (t+2) % 3
    STEP(t, bt, u2, bp, bq);           // even: consume bp, load bq
    STEP(t + 1, u1, bt, bq, bp);       // odd: consume bq, load bp; stage->bt
    bt = u2;
  }
#undef STEP
#undef LOADB
#undef STAGE

  // epilogue: lane holds 4 consecutive output-features (rows of A) at one token
#pragma unroll
  for (int mm = 0; mm < 8; ++mm) {
    int mrow = m0 + wr * 128 + mm * 16 + kseg * 4;
    float4 bv = *reinterpret_cast<const float4*>(&bias[e * M + mrow]);
#pragma unroll
    for (int nn = 0; nn < 4; ++nn) {
      int token = n0 + wc * 64 + nn * 16 + lrow;
      float v0 = acc[mm][nn][0] + bv.x;
      float v1 = acc[mm][nn][1] + bv.y;
      float v2 = acc[mm][nn][2] + bv.z;
      float v3 = acc[mm][nn][3] + bv.w;
      if (GELU) {
        v0 = gelu_fast(v0); v1 = gelu_fast(v1);
        v2 = gelu_fast(v2); v3 = gelu_fast(v3);
      }
      OutT* cp = C + ((size_t)e * CAP + token) * M + mrow;
      if constexpr (__is_same(OutT, __hip_bfloat16)) {
        short4v o;
        o[0] = (short)f2bf(v0); o[1] = (short)f2bf(v1);
        o[2] = (short)f2bf(v2); o[3] = (short)f2bf(v3);
        *reinterpret_cast<short4v*>(cp) = o;  // 8B store
      } else {
        float4 o = {v0, v1, v2, v3};
        *reinterpret_cast<float4*>(cp) = o;   // 16B store
      }
    }
  }
}

// ---------------- combine: per token, sum its <=2 weighted expert rows
__global__ void k_combine(const float* __restrict__ outbuf,
                          const int* __restrict__ token_slot,
                          const float2* __restrict__ tk_w,
                          float* __restrict__ comb) {
  int tid = threadIdx.x;
  int wid = tid >> 6, lane = tid & 63;
  int t = blockIdx.x * 4 + wid;
  int s0 = token_slot[2 * t], s1 = token_slot[2 * t + 1];
  float2 w = tk_w[t];
  float r[8] = {0.f, 0.f, 0.f, 0.f, 0.f, 0.f, 0.f, 0.f};
  if (s0 >= 0) {
    const float4* p = reinterpret_cast<const float4*>(outbuf + (size_t)s0 * ODIM + lane * 8);
    float4 a = p[0], b = p[1];
    r[0] += w.x * a.x; r[1] += w.x * a.y; r[2] += w.x * a.z; r[3] += w.x * a.w;
    r[4] += w.x * b.x; r[5] += w.x * b.y; r[6] += w.x * b.z; r[7] += w.x * b.w;
  }
  if (s1 >= 0) {
    const float4* p = reinterpret_cast<const float4*>(outbuf + (size_t)s1 * ODIM + lane * 8);
    float4 a = p[0], b = p[1];
    r[0] += w.y * a.x; r[1] += w.y * a.y; r[2] += w.y * a.z; r[3] += w.y * a.w;
    r[4] += w.y * b.x; r[5] += w.y * b.y; r[6] += w.y * b.z; r[7] += w.y * b.w;
  }
  float4* q = reinterpret_cast<float4*>(comb + (size_t)t * ODIM + lane * 8);
  float4 o0 = {r[0], r[1], r[2], r[3]};
  float4 o1 = {r[4], r[5], r[6], r[7]};
  q[0] = o0;
  q[1] = o1;
}

extern "C" void kernel_launch(void* const* d_in, const int* in_sizes, int n_in,
                              void* d_out, int out_size, void* d_ws, size_t ws_size,
                              hipStream_t stream) {
  const float* x      = (const float*)d_in[0];
  const float* gate_w = (const float*)d_in[1];
  const float* gate_b = (const float*)d_in[2];
  const float* w1     = (const float*)d_in[3];
  const float* b1     = (const float*)d_in[4];
  const float* w2     = (const float*)d_in[5];
  const float* b2     = (const float*)d_in[6];

  float* comb = (float*)d_out;                     // (8,2048,512) f32
  float* gate_probs = comb + (size_t)NTOK * ODIM;  // (16384,8) f32

  // workspace layout (~128.5 MiB; xg aliases outbuf - disjoint lifetimes)
  char* ws = (char*)d_ws;
  __hip_bfloat16* w1t    = (__hip_bfloat16*)(ws);              // [0,16M)   (E,H,D)
  __hip_bfloat16* w2t    = (__hip_bfloat16*)(ws + 16777216);   // [16,32M)  (E,O,H)
  __hip_bfloat16* hbuf   = (__hip_bfloat16*)(ws + 33554432);   // [32,96M)  (E,CAP,H)
  __hip_bfloat16* xg     = (__hip_bfloat16*)(ws + 100663296);  // [96,112M) (E,CAP,D)
  float*          outbuf = (float*)(ws + 100663296);           // [96,128M) (E,CAP,O)
  int*   expert_tokens   = (int*)(ws + 134217728);
  int2*  tk_e            = (int2*)(ws + 134283264);
  float2* tk_w           = (float2*)(ws + 134414336);
  int*   token_slot      = (int*)(ws + 134545408);

  k_prep<<<16384 + NTOK / 4, 256, 0, stream>>>(x, gate_w, gate_b, w1, w1t, w2, w2t,
                                               gate_probs, tk_e, tk_w, token_slot);
  k_dispatch<<<NE, 1024, 0, stream>>>(tk_e, token_slot, expert_tokens);
  k_gather<<<NE * CAP / 4, 256, 0, stream>>>(x, expert_tokens, xg);
  // GEMM1: A=w1t (E,H,D) M=HDIM, B=xg, C=hbuf (E,CAP,H) bf16 + GELU
  k_gemm<DDIM, HDIM, true, __hip_bfloat16>
      <<<dim3(CAP / 128, HDIM / 256, NE), 256, 0, stream>>>(w1t, xg, b1, hbuf);
  // GEMM2: A=w2t (E,O,H) M=ODIM, B=hbuf, C=outbuf (E,CAP,O) f32
  k_gemm<HDIM, ODIM, false, float>
      <<<dim3(CAP / 128, ODIM / 256, NE), 256, 0, stream>>>(w2t, hbuf, b2, outbuf);
  k_combine<<<NTOK / 4, 256, 0, stream>>>(outbuf, token_slot, tk_w, comb);
}

// Round 8
// 189.582 us; speedup vs baseline: 1.1460x; 1.1460x over previous
//
#include <hip/hip_runtime.h>
#include <hip/hip_bf16.h>

// Problem constants (SparseMoE: D=512, H=2048, O=512, E=8, K=2, CF=1.0)
#define NTOK 16384
#define DDIM 512
#define HDIM 2048
#define ODIM 512
#define NE 8
#define CAP 2048   // max(int(N/E*CF), 4) = 2048

typedef __attribute__((ext_vector_type(8))) short short8v;
typedef __attribute__((ext_vector_type(4))) short short4v;
typedef __attribute__((ext_vector_type(8))) unsigned short ushort8v;
typedef __attribute__((ext_vector_type(4))) float f32x4;

static __device__ __forceinline__ unsigned short f2bf(float f) {
  __hip_bfloat16 h = __float2bfloat16(f);
  return __builtin_bit_cast(unsigned short, h);
}

// async global->LDS, 16B per lane; LDS dest = wave-uniform base + lane*16
#define GLOAD_LDS16(gp, lp)                                               \
  __builtin_amdgcn_global_load_lds(                                       \
      (const __attribute__((address_space(1))) void*)(gp),                \
      (__attribute__((address_space(3))) void*)(lp), 16, 0, 0)

// ---------------- fused prep: transpose w1, transpose w2, gating
__device__ __forceinline__ void transpose_block(const float* __restrict__ src,
                                                __hip_bfloat16* __restrict__ dst,
                                                int R, int C, int b) {
  __shared__ float tile[32][33];
  int nx = C >> 5, ny = R >> 5;
  int x = b % nx, y = (b / nx) % ny, e = b / (nx * ny);
  size_t base = (size_t)e * R * C;
  int c0 = x * 32, r0 = y * 32;
  int tx = threadIdx.x & 31, ty = threadIdx.x >> 5;
#pragma unroll
  for (int i = 0; i < 32; i += 8)
    tile[ty + i][tx] = src[base + (size_t)(r0 + ty + i) * C + c0 + tx];
  __syncthreads();
#pragma unroll
  for (int i = 0; i < 32; i += 8)
    dst[base + (size_t)(c0 + ty + i) * R + r0 + tx] = __float2bfloat16(tile[tx][ty + i]);
}

__global__ void k_prep(const float* __restrict__ x, const float* __restrict__ gw,
                       const float* __restrict__ gb, const float* __restrict__ w1,
                       __hip_bfloat16* __restrict__ w1t, const float* __restrict__ w2,
                       __hip_bfloat16* __restrict__ w2t, float* __restrict__ gate_probs,
                       int2* __restrict__ tk_e, float2* __restrict__ tk_w,
                       int* __restrict__ token_slot) {
  int b = blockIdx.x;
  if (b < 8192) { transpose_block(w1, w1t, DDIM, HDIM, b); return; }
  if (b < 16384) { transpose_block(w2, w2t, HDIM, ODIM, b - 8192); return; }
  b -= 16384;
  __shared__ float gws[DDIM * 9];
  int tid = threadIdx.x;
  for (int i = tid; i < DDIM * NE; i += 256) {
    int d = i >> 3, e = i & 7;
    gws[d * 9 + e] = gw[i];
  }
  __syncthreads();
  int wid = tid >> 6, lane = tid & 63;
  int t = b * 4 + wid;
  const float* xr = x + (size_t)t * DDIM;
  float acc[NE] = {0.f, 0.f, 0.f, 0.f, 0.f, 0.f, 0.f, 0.f};
#pragma unroll
  for (int j = 0; j < 8; ++j) {
    float xv = xr[lane + 64 * j];
    const float* g = &gws[(lane + 64 * j) * 9];
#pragma unroll
    for (int e = 0; e < NE; ++e) acc[e] += xv * g[e];
  }
#pragma unroll
  for (int e = 0; e < NE; ++e) {
#pragma unroll
    for (int off = 32; off > 0; off >>= 1) acc[e] += __shfl_xor(acc[e], off, 64);
  }
  if (lane == 0) {
    float p[NE];
    float m = -1e30f;
#pragma unroll
    for (int e = 0; e < NE; ++e) { p[e] = acc[e] + gb[e]; m = fmaxf(m, p[e]); }
    float s = 0.f;
#pragma unroll
    for (int e = 0; e < NE; ++e) { p[e] = expf(p[e] - m); s += p[e]; }
    float inv = 1.f / s;
#pragma unroll
    for (int e = 0; e < NE; ++e) { p[e] *= inv; gate_probs[(size_t)t * NE + e] = p[e]; }
    int i1 = 0; float p1 = p[0];
#pragma unroll
    for (int e = 1; e < NE; ++e) if (p[e] > p1) { p1 = p[e]; i1 = e; }
    int i2 = -1; float p2 = -1e30f;
#pragma unroll
    for (int e = 0; e < NE; ++e) if (e != i1 && p[e] > p2) { p2 = p[e]; i2 = e; }
    float wsum = p1 + p2;
    tk_e[t] = make_int2(i1, i2);
    tk_w[t] = make_float2(p1 / wsum, p2 / wsum);
    token_slot[2 * t] = -1;
    token_slot[2 * t + 1] = -1;
  }
}

// ---------------- dispatch: per-expert FCFS capacity assignment (block scan)
__global__ void k_dispatch(const int2* __restrict__ tk_e, int* __restrict__ token_slot,
                           int* __restrict__ expert_tokens) {
  int e = blockIdx.x;
  int tid = threadIdx.x;
  int lane = tid & 63, w = tid >> 6;   // 16 waves
  __shared__ int wave_cnt[16];
  int base = 0;
  for (int chunk = 0; chunk < NTOK / 1024; ++chunk) {
    int t = chunk * 1024 + tid;
    int2 te = tk_e[t];
    int k = (te.x == e) ? 0 : ((te.y == e) ? 1 : -1);
    bool flag = (k >= 0);
    unsigned long long m = __ballot(flag);
    int pre = __popcll(m & ((1ull << lane) - 1ull));
    __syncthreads();
    if (lane == 0) wave_cnt[w] = __popcll(m);
    __syncthreads();
    int off = 0, total = 0;
#pragma unroll
    for (int i = 0; i < 16; ++i) {
      off += (i < w) ? wave_cnt[i] : 0;
      total += wave_cnt[i];
    }
    int rank = base + off + pre;
    if (flag && rank < CAP) {
      expert_tokens[e * CAP + rank] = t;
      token_slot[2 * t + k] = e * CAP + rank;
    }
    base += total;
  }
  int nvalid = base < CAP ? base : CAP;
  for (int s = nvalid + tid; s < CAP; s += 1024)
    expert_tokens[e * CAP + s] = 0;  // padded slots: weight 0, never combined
}

// ---------------- gather: xg[e][c][:] = bf16(x[expert_tokens[e*CAP+c]][:])
__global__ void k_gather(const float* __restrict__ x,
                         const int* __restrict__ expert_tokens,
                         __hip_bfloat16* __restrict__ xg) {
  int tid = threadIdx.x, wid = tid >> 6, lane = tid & 63;
  int slot = blockIdx.x * 4 + wid;  // 0..E*CAP-1
  int tok = expert_tokens[slot];
  const float4* src = reinterpret_cast<const float4*>(x + (size_t)tok * DDIM) + lane * 2;
  float4 u = src[0], v = src[1];
  ushort8v o;
  o[0] = f2bf(u.x); o[1] = f2bf(u.y); o[2] = f2bf(u.z); o[3] = f2bf(u.w);
  o[4] = f2bf(v.x); o[5] = f2bf(v.y); o[6] = f2bf(v.z); o[7] = f2bf(v.w);
  *reinterpret_cast<ushort8v*>(xg + (size_t)slot * DDIM + lane * 8) = o;
}

// sigmoid-form tanh-GELU: |err vs exact erf-gelu| < ~1e-3, safe for bf16 out
static __device__ __forceinline__ float gelu_fast(float v) {
  float z = 1.5957691216057308f * (v + 0.044715f * v * v * v);
  return v / (1.f + __expf(-z));
}

// ---------------- m201-style 256x256 8-phase GEMM. BK=64, 512 threads,
// 8 waves (2M x 4N), wave-tile 128x64. LDS 128 KB: 2 bufs x (A 32K | B 32K).
// Per K-tile: 4 phases of {ds-read subtile, stage 1 half-tile (2 gload_lds),
// barrier, lgkmcnt(0)+sched_barrier, setprio(1) 16 MFMA setprio(0), barrier}.
// Stage cursor: t.ph0/1 -> (t+1).A halves (other buf); t.ph2/3 -> (t+2).B
// halves (current buf; B last read at ph1 -> region-safe).
// vmcnt(4) at tile boundaries (2 halves in flight); vmcnt(0) at final.
// Swizzle (rule 21): 128B rows, 16B slot s' holds global slot s'^(row&7);
// applied on global source (linear gload_lds dest) and on ds_read.
template <int K, int M, bool GELU, typename OutT>
__global__ __launch_bounds__(512, 2) void k_gemm8(
    const __hip_bfloat16* __restrict__ A, const __hip_bfloat16* __restrict__ B,
    const float* __restrict__ bias, OutT* __restrict__ C) {
  __shared__ char lds[131072];
  constexpr int T = K / 64;  // K-tiles: 8 (GEMM1), 32 (GEMM2)
  // XCD-aware bijective remap (grid total is a multiple of 8)
  int gx = gridDim.x, gy = gridDim.y;
  int lin = (blockIdx.z * gy + blockIdx.y) * gx + blockIdx.x;
  int total = gx * gy * (int)gridDim.z;
  int cpx = total >> 3;
  lin = (lin & 7) * cpx + (lin >> 3);
  int gxy = gx * gy;
  int e = lin / gxy;
  int rem = lin - e * gxy;
  int mt = rem / gx, nt = rem - mt * gx;

  const int m0 = mt * 256, n0 = nt * 256;
  const int tid = threadIdx.x;
  const int lane = tid & 63, wid = tid >> 6;
  const int wm = wid >> 2, wn = wid & 3;   // 2M x 4N waves; wave-tile 128x64
  const int lrow = lane & 15, kseg = lane >> 4;

  // staging constants: 512 thr x 16B = 8KB/round; half-tile = 128 rows = 2 rounds
  const int srow8 = tid >> 3;                      // 0..63
  const int ssl = (tid & 7) ^ ((tid >> 3) & 7);    // inverse-swizzled src slot
  const __hip_bfloat16* Ab = A + ((size_t)e * M + m0) * K;
  const __hip_bfloat16* Bb = B + ((size_t)e * CAP + n0) * K;

#define ST_A(tt, h, buf)                                                       \
  do {                                                                         \
    _Pragma("unroll")                                                          \
    for (int j = 0; j < 2; ++j)                                                \
      GLOAD_LDS16(Ab + (size_t)((h) * 128 + j * 64 + srow8) * K +              \
                      (size_t)(tt) * 64 + ssl * 8,                             \
                  lds + (buf) * 65536 + (h) * 16384 + j * 8192 + tid * 16);    \
  } while (0)

#define ST_B(tt, h, buf)                                                       \
  do {                                                                         \
    _Pragma("unroll")                                                          \
    for (int j = 0; j < 2; ++j)                                                \
      GLOAD_LDS16(Bb + (size_t)((h) * 128 + j * 64 + srow8) * K +              \
                      (size_t)(tt) * 64 + ssl * 8,                             \
                  lds + (buf) * 65536 + 32768 + (h) * 16384 + j * 8192 +       \
                      tid * 16);                                               \
  } while (0)

#define READ_A(dst, buf, mh)                                                   \
  do {                                                                         \
    _Pragma("unroll")                                                          \
    for (int mm = 0; mm < 4; ++mm)                                             \
      _Pragma("unroll")                                                        \
      for (int ks = 0; ks < 2; ++ks) {                                         \
        int rr = wm * 128 + (mh) * 64 + mm * 16 + lrow;                        \
        int slot = (ks * 4 + kseg) ^ (rr & 7);                                 \
        dst[mm][ks] = *reinterpret_cast<const short8v*>(                       \
            lds + (buf) * 65536 + rr * 128 + slot * 16);                       \
      }                                                                        \
  } while (0)

#define READ_B(dst, buf, nh)                                                   \
  do {                                                                         \
    _Pragma("unroll")                                                          \
    for (int nn = 0; nn < 2; ++nn)                                             \
      _Pragma("unroll")                                                        \
      for (int ks = 0; ks < 2; ++ks) {                                         \
        int rn = wn * 64 + (nh) * 32 + nn * 16 + lrow;                         \
        int slot = (ks * 4 + kseg) ^ (rn & 7);                                 \
        dst[nn][ks] = *reinterpret_cast<const short8v*>(                       \
            lds + (buf) * 65536 + 32768 + rn * 128 + slot * 16);               \
      }                                                                        \
  } while (0)

#define MFMA_Q(Af, Bf, mh, nh)                                                 \
  do {                                                                         \
    _Pragma("unroll")                                                          \
    for (int mm = 0; mm < 4; ++mm)                                             \
      _Pragma("unroll")                                                        \
      for (int nn = 0; nn < 2; ++nn)                                           \
        _Pragma("unroll")                                                      \
        for (int ks = 0; ks < 2; ++ks)                                         \
          acc[(mh) * 4 + mm][(nh) * 2 + nn] =                                  \
              __builtin_amdgcn_mfma_f32_16x16x32_bf16(                         \
                  Af[mm][ks], Bf[nn][ks], acc[(mh) * 4 + mm][(nh) * 2 + nn],   \
                  0, 0, 0);                                                    \
  } while (0)

#define PH_MID()                                                               \
  do {                                                                         \
    __builtin_amdgcn_s_barrier();                                              \
    asm volatile("s_waitcnt lgkmcnt(0)" ::: "memory");                         \
    __builtin_amdgcn_sched_barrier(0);                                         \
  } while (0)

#define TILEB(t, buf, VM)                                                      \
  do {                                                                         \
    /* ph0: (mh0,nh0) */                                                       \
    READ_A(Ar0, buf, 0);                                                       \
    READ_B(Br0, buf, 0);                                                       \
    if ((t) + 1 < T) { ST_A((t) + 1, 0, (buf) ^ 1); }                          \
    PH_MID();                                                                  \
    __builtin_amdgcn_s_setprio(1);                                             \
    MFMA_Q(Ar0, Br0, 0, 0);                                                    \
    __builtin_amdgcn_s_setprio(0);                                             \
    __builtin_amdgcn_s_barrier();                                              \
    /* ph1: (mh0,nh1) */                                                       \
    READ_B(Br1, buf, 1);                                                       \
    if ((t) + 1 < T) { ST_A((t) + 1, 1, (buf) ^ 1); }                          \
    PH_MID();                                                                  \
    __builtin_amdgcn_s_setprio(1);                                             \
    MFMA_Q(Ar0, Br1, 0, 1);                                                    \
    __builtin_amdgcn_s_setprio(0);                                             \
    __builtin_amdgcn_s_barrier();                                              \
    /* ph2: (mh1,nh0) */                                                       \
    READ_A(Ar1, buf, 1);                                                       \
    if ((t) + 2 < T) { ST_B((t) + 2, 0, (buf)); }                              \
    PH_MID();                                                                  \
    __builtin_amdgcn_s_setprio(1);                                             \
    MFMA_Q(Ar1, Br0, 1, 0);                                                    \
    __builtin_amdgcn_s_setprio(0);                                             \
    __builtin_amdgcn_s_barrier();                                              \
    /* ph3: (mh1,nh1) */                                                       \
    if ((t) + 2 < T) { ST_B((t) + 2, 1, (buf)); }                              \
    __builtin_amdgcn_s_barrier();                                              \
    __builtin_amdgcn_s_setprio(1);                                             \
    MFMA_Q(Ar1, Br1, 1, 1);                                                    \
    __builtin_amdgcn_s_setprio(0);                                             \
    asm volatile("s_waitcnt vmcnt(" VM ")" ::: "memory");                      \
    __builtin_amdgcn_sched_barrier(0);                                         \
    __builtin_amdgcn_s_barrier();                                              \
  } while (0)

  f32x4 acc[8][4] = {};
  short8v Ar0[4][2], Ar1[4][2], Br0[2][2], Br1[2][2];

  // prologue: t0 (A+B) -> buf0; t1.B -> buf1; (t1.A staged in tile0 ph0/1)
  ST_A(0, 0, 0); ST_A(0, 1, 0); ST_B(0, 0, 0); ST_B(0, 1, 0);
  ST_B(1, 0, 1); ST_B(1, 1, 1);
  asm volatile("s_waitcnt vmcnt(4)" ::: "memory");  // t0 resident
  __builtin_amdgcn_sched_barrier(0);
  __builtin_amdgcn_s_barrier();

  for (int i = 0; i < T / 2 - 1; ++i) {
    TILEB(2 * i, 0, "4");
    TILEB(2 * i + 1, 1, "4");
  }
  TILEB(T - 2, 0, "0");
  TILEB(T - 1, 1, "0");

#undef TILEB
#undef PH_MID
#undef MFMA_Q
#undef READ_B
#undef READ_A
#undef ST_B
#undef ST_A

  // epilogue: lane holds 4 consecutive output-features (rows of A) at one token
#pragma unroll
  for (int mi = 0; mi < 8; ++mi) {
    int mrow = m0 + wm * 128 + mi * 16 + kseg * 4;
    float4 bv = *reinterpret_cast<const float4*>(&bias[e * M + mrow]);
#pragma unroll
    for (int ni = 0; ni < 4; ++ni) {
      int token = n0 + wn * 64 + ni * 16 + lrow;
      float v0 = acc[mi][ni][0] + bv.x;
      float v1 = acc[mi][ni][1] + bv.y;
      float v2 = acc[mi][ni][2] + bv.z;
      float v3 = acc[mi][ni][3] + bv.w;
      if (GELU) {
        v0 = gelu_fast(v0); v1 = gelu_fast(v1);
        v2 = gelu_fast(v2); v3 = gelu_fast(v3);
      }
      OutT* cp = C + ((size_t)e * CAP + token) * M + mrow;
      if constexpr (__is_same(OutT, __hip_bfloat16)) {
        short4v o;
        o[0] = (short)f2bf(v0); o[1] = (short)f2bf(v1);
        o[2] = (short)f2bf(v2); o[3] = (short)f2bf(v3);
        *reinterpret_cast<short4v*>(cp) = o;  // 8B store
      } else {
        float4 o = {v0, v1, v2, v3};
        *reinterpret_cast<float4*>(cp) = o;   // 16B store
      }
    }
  }
}

// ---------------- combine: per token, sum its <=2 weighted expert rows
__global__ void k_combine(const float* __restrict__ outbuf,
                          const int* __restrict__ token_slot,
                          const float2* __restrict__ tk_w,
                          float* __restrict__ comb) {
  int tid = threadIdx.x;
  int wid = tid >> 6, lane = tid & 63;
  int t = blockIdx.x * 4 + wid;
  int s0 = token_slot[2 * t], s1 = token_slot[2 * t + 1];
  float2 w = tk_w[t];
  float r[8] = {0.f, 0.f, 0.f, 0.f, 0.f, 0.f, 0.f, 0.f};
  if (s0 >= 0) {
    const float4* p = reinterpret_cast<const float4*>(outbuf + (size_t)s0 * ODIM + lane * 8);
    float4 a = p[0], b = p[1];
    r[0] += w.x * a.x; r[1] += w.x * a.y; r[2] += w.x * a.z; r[3] += w.x * a.w;
    r[4] += w.x * b.x; r[5] += w.x * b.y; r[6] += w.x * b.z; r[7] += w.x * b.w;
  }
  if (s1 >= 0) {
    const float4* p = reinterpret_cast<const float4*>(outbuf + (size_t)s1 * ODIM + lane * 8);
    float4 a = p[0], b = p[1];
    r[0] += w.y * a.x; r[1] += w.y * a.y; r[2] += w.y * a.z; r[3] += w.y * a.w;
    r[4] += w.y * b.x; r[5] += w.y * b.y; r[6] += w.y * b.z; r[7] += w.y * b.w;
  }
  float4* q = reinterpret_cast<float4*>(comb + (size_t)t * ODIM + lane * 8);
  float4 o0 = {r[0], r[1], r[2], r[3]};
  float4 o1 = {r[4], r[5], r[6], r[7]};
  q[0] = o0;
  q[1] = o1;
}

extern "C" void kernel_launch(void* const* d_in, const int* in_sizes, int n_in,
                              void* d_out, int out_size, void* d_ws, size_t ws_size,
                              hipStream_t stream) {
  const float* x      = (const float*)d_in[0];
  const float* gate_w = (const float*)d_in[1];
  const float* gate_b = (const float*)d_in[2];
  const float* w1     = (const float*)d_in[3];
  const float* b1     = (const float*)d_in[4];
  const float* w2     = (const float*)d_in[5];
  const float* b2     = (const float*)d_in[6];

  float* comb = (float*)d_out;                     // (8,2048,512) f32
  float* gate_probs = comb + (size_t)NTOK * ODIM;  // (16384,8) f32

  // workspace layout (~128.5 MiB; xg aliases outbuf - disjoint lifetimes)
  char* ws = (char*)d_ws;
  __hip_bfloat16* w1t    = (__hip_bfloat16*)(ws);              // [0,16M)   (E,H,D)
  __hip_bfloat16* w2t    = (__hip_bfloat16*)(ws + 16777216);   // [16,32M)  (E,O,H)
  __hip_bfloat16* hbuf   = (__hip_bfloat16*)(ws + 33554432);   // [32,96M)  (E,CAP,H)
  __hip_bfloat16* xg     = (__hip_bfloat16*)(ws + 100663296);  // [96,112M) (E,CAP,D)
  float*          outbuf = (float*)(ws + 100663296);           // [96,128M) (E,CAP,O)
  int*   expert_tokens   = (int*)(ws + 134217728);
  int2*  tk_e            = (int2*)(ws + 134283264);
  float2* tk_w           = (float2*)(ws + 134414336);
  int*   token_slot      = (int*)(ws + 134545408);

  k_prep<<<16384 + NTOK / 4, 256, 0, stream>>>(x, gate_w, gate_b, w1, w1t, w2, w2t,
                                               gate_probs, tk_e, tk_w, token_slot);
  k_dispatch<<<NE, 1024, 0, stream>>>(tk_e, token_slot, expert_tokens);
  k_gather<<<NE * CAP / 4, 256, 0, stream>>>(x, expert_tokens, xg);
  // GEMM1: A=w1t (E,H,D) M=HDIM, B=xg, C=hbuf (E,CAP,H) bf16 + GELU
  k_gemm8<DDIM, HDIM, true, __hip_bfloat16>
      <<<dim3(CAP / 256, HDIM / 256, NE), 512, 0, stream>>>(w1t, xg, b1, hbuf);
  // GEMM2: A=w2t (E,O,H) M=ODIM, B=hbuf, C=outbuf (E,CAP,O) f32
  k_gemm8<HDIM, ODIM, false, float>
      <<<dim3(CAP / 256, ODIM / 256, NE), 512, 0, stream>>>(w2t, hbuf, b2, outbuf);
  k_combine<<<NTOK / 4, 256, 0, stream>>>(outbuf, token_slot, tk_w, comb);
}